// Round 11
// baseline (1172.392 us; speedup 1.0000x reference)
//
#include <hip/hip_runtime.h>
#include <hip/hip_bf16.h>

#define B_ 32
#define T_ 512
#define L_ 16
#define F_ 128
#define H_ 128
#define C_ 61
#define NF_ (B_*T_)   // 16384 frames
#define CH_ 4096      // frames per rnn1 chunk

typedef unsigned int u32;
typedef unsigned short u16;
typedef __attribute__((ext_vector_type(8))) short s16x8;
typedef __attribute__((ext_vector_type(4))) float f32x4;

__device__ __forceinline__ float bflo(u32 v){ return __uint_as_float(v << 16); }
__device__ __forceinline__ float bfhi(u32 v){ return __uint_as_float(v & 0xffff0000u); }
__device__ __forceinline__ u16 f2bf(float f){
  u32 u = __float_as_uint(f);
  u += 0x7fffu + ((u >> 16) & 1u);
  return (u16)(u >> 16);
}
__device__ __forceinline__ u32 pack2(float a, float b){
  return (u32)f2bf(a) | ((u32)f2bf(b) << 16);
}
__device__ __forceinline__ u32 cvt_pk_bf16(float a, float b){
  u32 d;
  asm("v_cvt_pk_bf16_f32 %0, %1, %2" : "=v"(d) : "v"(a), "v"(b));
  return d;
}
__device__ __forceinline__ float fast_tanh(float x){
  float e = __expf(2.f*x);
  return 1.f - 2.f*__builtin_amdgcn_rcpf(e + 1.f);
}
__device__ __forceinline__ float fast_sigmoid(float x){
  return __builtin_amdgcn_rcpf(1.f + __expf(-x));
}
__device__ __forceinline__ f32x4 mfma16(s16x8 a, s16x8 b, f32x4 c){
  return __builtin_amdgcn_mfma_f32_16x16x32_bf16(a, b, c, 0, 0, 0);
}
// LDS-only barrier: does NOT drain vmcnt (global prefetch loads / stores
// stay in flight), unlike __syncthreads which drains vmcnt(0).
__device__ __forceinline__ void lds_barrier(){
  asm volatile("s_waitcnt lgkmcnt(0)\n\ts_barrier" ::: "memory");
}
// pack 8 consecutive f32 (two float4) into a bf16x8 fragment, k-order
__device__ __forceinline__ s16x8 packfrag(const float* p){
  const float4 a = *(const float4*)p;
  const float4 b = *(const float4*)(p+4);
  union { s16x8 v; u32 w[4]; } f;
  f.w[0]=pack2(a.x,a.y); f.w[1]=pack2(a.z,a.w);
  f.w[2]=pack2(b.x,b.y); f.w[3]=pack2(b.z,b.w);
  return f.v;
}

// ---------------------------------------------------------------------------
// rnn1 layer 0 via MFMA. 16 frames/WG. Coalesced post-barrier LDS flush for
// the out stores (kept from round 10 — part of the 27us non-gru win).
// ---------------------------------------------------------------------------
__global__ __launch_bounds__(256) void l0_mfma(
    const float* __restrict__ x,      // (CH,16,128) chunk base
    const float* __restrict__ Wih,    // (2,128,128)
    const float* __restrict__ Whh,    // (2,128,128)
    const float* __restrict__ bih,    // (2,128)
    const float* __restrict__ bhh,    // (2,128)
    u16* __restrict__ out)            // (CH,16,256) bf16
{
  __shared__ __align__(16) u16 Hb[2][16][136];
  __shared__ __align__(16) u16 Xb[2][16][136];
  const int t = threadIdx.x;
  const int lane = t & 63, wv = t >> 6;
  const int l15 = lane & 15, kg = lane >> 4;
  const int dir = blockIdx.y;
  const int f0 = blockIdx.x * 16;
  s16x8 wih[2][4], whh[2][4];
  {
    const float* Wid = Wih + dir*16384;
    const float* Whd = Whh + dir*16384;
    #pragma unroll
    for (int nt = 0; nt < 2; nt++){
      const int u = wv*32 + nt*16 + l15;
      #pragma unroll
      for (int kc = 0; kc < 4; kc++){
        const int k = kc*32 + kg*8;
        wih[nt][kc] = packfrag(&Wid[u*128 + k]);
        whh[nt][kc] = packfrag(&Whd[u*128 + k]);
      }
    }
  }
  const float bv0 = bih[dir*128 + wv*32 + l15]      + bhh[dir*128 + wv*32 + l15];
  const float bv1 = bih[dir*128 + wv*32 + 16 + l15] + bhh[dir*128 + wv*32 + 16 + l15];
  const f32x4 bs0 = {bv0,bv0,bv0,bv0}, bs1 = {bv1,bv1,bv1,bv1};
  const int sr = t >> 4, sc8 = (t & 15) * 8;   // stage: frame row, col (8 f32)
  // flush role: frame ff, unit-block u8 (16 threads x 16B = one frame row)
  const int ff = t >> 4, u8 = (t & 15) * 8;
  u16* opbase = out + (size_t)f0*4096 + dir*128;
  int opoff = ff*4096 + (dir ? 15 : 0)*256 + u8;
  const int opstep = dir ? -256 : 256;
  for (int idx = t; idx < 272; idx += 256)
    ((uint4*)&Hb[0][0][0])[idx] = make_uint4(0,0,0,0);
  {
    const int s0 = dir ? 15 : 0;
    const float4* xp = (const float4*)&x[(size_t)(f0+sr)*2048 + s0*128 + sc8];
    const float4 v0 = xp[0], v1 = xp[1];
    *(uint4*)&Xb[0][sr][sc8] = make_uint4(pack2(v0.x,v0.y),pack2(v0.z,v0.w),
                                          pack2(v1.x,v1.y),pack2(v1.z,v1.w));
  }
  lds_barrier();
  int cur = 0;
  for (int st = 0; st < 16; st++){
    float4 p0,p1;
    if (st < 15){
      const int sn = dir ? (14-st) : (st+1);
      const float4* xp = (const float4*)&x[(size_t)(f0+sr)*2048 + sn*128 + sc8];
      p0 = xp[0]; p1 = xp[1];
    }
    f32x4 acc0 = bs0, acc1 = bs1;
    #pragma unroll
    for (int kc = 0; kc < 4; kc++){
      const int ko = kc*32 + kg*8;
      const s16x8 ax = *(const s16x8*)&Xb[cur][l15][ko];
      const s16x8 ah = *(const s16x8*)&Hb[cur][l15][ko];
      acc0 = mfma16(ax, wih[0][kc], acc0);
      acc1 = mfma16(ax, wih[1][kc], acc1);
      acc0 = mfma16(ah, whh[0][kc], acc0);
      acc1 = mfma16(ah, whh[1][kc], acc1);
    }
    const int u0 = wv*32 + l15, u1 = wv*32 + 16 + l15;
    #pragma unroll
    for (int r = 0; r < 4; r++){
      const int m = kg*4 + r;
      Hb[cur^1][m][u0] = f2bf(fast_tanh(acc0[r]));
      Hb[cur^1][m][u1] = f2bf(fast_tanh(acc1[r]));
    }
    if (st < 15){
      *(uint4*)&Xb[cur^1][sr][sc8] = make_uint4(pack2(p0.x,p0.y),pack2(p0.z,p0.w),
                                                pack2(p1.x,p1.y),pack2(p1.z,p1.w));
    }
    lds_barrier();
    // coalesced flush of this step's h (reads the buffer just written)
    {
      const uint4 hv = *(const uint4*)&Hb[cur^1][ff][u8];
      *(uint4*)&opbase[opoff] = hv;
      opoff += opstep;
    }
    cur ^= 1;
  }
}

// ---------------------------------------------------------------------------
// rnn1 layer 1 FORWARD via MFMA, 16 frames/WG + FUSED l1-backward single-step
// GEMM at st==15 (kept from round 10).
// ---------------------------------------------------------------------------
__global__ __launch_bounds__(256) void l1f_mfma(
    const u16* __restrict__ U,        // (CH,16,256) bf16
    const float* __restrict__ Wih,    // (2,128,256) dir0
    const float* __restrict__ Whh,    // (2,128,128) dir0
    const float* __restrict__ bih,    // (2,128)
    const float* __restrict__ bhh,
    const u16* __restrict__ r1Wb,     // (128,256) bf16 = dir1 Wih
    const float* __restrict__ biasb,  // (128) dir1 bih+bhh
    u16* __restrict__ out)            // rnn1 rows (ld 256)
{
  __shared__ __align__(16) u16 Hb[2][16][136];
  __shared__ __align__(16) u16 Xb[2][16][264];
  const int t = threadIdx.x;
  const int lane = t & 63, wv = t >> 6;
  const int l15 = lane & 15, kg = lane >> 4;
  const int f0 = blockIdx.x * 16;
  s16x8 wih[2][8], whh[2][4];
  {
    #pragma unroll
    for (int nt = 0; nt < 2; nt++){
      const int u = wv*32 + nt*16 + l15;
      #pragma unroll
      for (int kc = 0; kc < 8; kc++)
        wih[nt][kc] = packfrag(&Wih[u*256 + kc*32 + kg*8]);
      #pragma unroll
      for (int kc = 0; kc < 4; kc++)
        whh[nt][kc] = packfrag(&Whh[u*128 + kc*32 + kg*8]);
    }
  }
  const float bv0 = bih[wv*32 + l15]      + bhh[wv*32 + l15];
  const float bv1 = bih[wv*32 + 16 + l15] + bhh[wv*32 + 16 + l15];
  const f32x4 bs0 = {bv0,bv0,bv0,bv0}, bs1 = {bv1,bv1,bv1,bv1};
  const int sr = t >> 4, scu = (t & 15) * 16;
  for (int idx = t; idx < 272; idx += 256)
    ((uint4*)&Hb[0][0][0])[idx] = make_uint4(0,0,0,0);
  {
    const uint4* up = (const uint4*)&U[(size_t)(f0+sr)*4096 + scu];
    uint4 c0 = up[0], c1 = up[1];
    *(uint4*)&Xb[0][sr][scu]   = c0;
    *(uint4*)&Xb[0][sr][scu+8] = c1;
  }
  lds_barrier();
  int cur = 0;
  for (int st = 0; st < 16; st++){
    uint4 c0,c1;
    if (st < 15){
      const uint4* up = (const uint4*)&U[(size_t)(f0+sr)*4096 + (st+1)*256 + scu];
      c0 = up[0]; c1 = up[1];
    }
    f32x4 acc0 = bs0, acc1 = bs1;
    #pragma unroll
    for (int kc = 0; kc < 8; kc++){
      const s16x8 ax = *(const s16x8*)&Xb[cur][l15][kc*32 + kg*8];
      acc0 = mfma16(ax, wih[0][kc], acc0);
      acc1 = mfma16(ax, wih[1][kc], acc1);
    }
    #pragma unroll
    for (int kc = 0; kc < 4; kc++){
      const s16x8 ah = *(const s16x8*)&Hb[cur][l15][kc*32 + kg*8];
      acc0 = mfma16(ah, whh[0][kc], acc0);
      acc1 = mfma16(ah, whh[1][kc], acc1);
    }
    const int u0 = wv*32 + l15, u1 = wv*32 + 16 + l15;
    #pragma unroll
    for (int r = 0; r < 4; r++){
      const int m = kg*4 + r;
      const u16 h0 = f2bf(fast_tanh(acc0[r]));
      const u16 h1 = f2bf(fast_tanh(acc1[r]));
      Hb[cur^1][m][u0] = h0;
      Hb[cur^1][m][u1] = h1;
      if (st == 15){
        out[(size_t)(f0+m)*256 + u0] = h0;
        out[(size_t)(f0+m)*256 + u1] = h1;
      }
    }
    if (st == 15){
      // fused l1-backward @ s=15: tanh(U15 @ Wihb^T + biasb), cols 128..255
      const float bb0 = biasb[wv*32 + l15];
      const float bb1 = biasb[wv*32 + 16 + l15];
      f32x4 ab0 = {bb0,bb0,bb0,bb0}, ab1 = {bb1,bb1,bb1,bb1};
      #pragma unroll
      for (int kc = 0; kc < 8; kc++){
        const s16x8 uf = *(const s16x8*)&Xb[cur][l15][kc*32 + kg*8];
        const s16x8 w0 = *(const s16x8*)&r1Wb[(size_t)(wv*32 + l15)*256 + kc*32 + kg*8];
        const s16x8 w1 = *(const s16x8*)&r1Wb[(size_t)(wv*32 + 16 + l15)*256 + kc*32 + kg*8];
        ab0 = mfma16(uf, w0, ab0);
        ab1 = mfma16(uf, w1, ab1);
      }
      #pragma unroll
      for (int r = 0; r < 4; r++){
        const int m = kg*4 + r;
        out[(size_t)(f0+m)*256 + 128 + wv*32 + l15]      = f2bf(fast_tanh(ab0[r]));
        out[(size_t)(f0+m)*256 + 128 + wv*32 + 16 + l15] = f2bf(fast_tanh(ab1[r]));
      }
    }
    if (st < 15){
      *(uint4*)&Xb[cur^1][sr][scu]   = c0;
      *(uint4*)&Xb[cur^1][sr][scu+8] = c1;
    }
    lds_barrier();
    cur ^= 1;
  }
}

// ---------------------------------------------------------------------------
// xw GEMM, operand-swapped, coalesced 16B stores into plane layout
// xw4[d][g][tt][b][128u] f32 (kept from round 10).
// ---------------------------------------------------------------------------
__global__ __launch_bounds__(256) void gemm_xw(
    const u16* __restrict__ A,       // (16384,256) bf16 activations
    const u16* __restrict__ Wb,      // (768,256) bf16 weights
    const float* __restrict__ bih,   // (768)
    const float* __restrict__ bhhp,  // (768)
    float* __restrict__ xw4)         // (2,3,512,32,128) f32
{
  const int t = threadIdx.x;
  const int lane = t & 63, wv = t >> 6;
  const int l15 = lane & 15, kg = lane >> 4;
  const int ublk = blockIdx.x * 32;              // unit-block (24 blocks)
  const int f0 = blockIdx.y * 64 + wv*16;        // frame-block, 16/wave
  const u16* Ap = A  + (size_t)(f0 + l15)*256 + kg*8;
  const u16* W0 = Wb + (size_t)(ublk + l15)*256 + kg*8;
  const u16* W1 = Wb + (size_t)(ublk + 16 + l15)*256 + kg*8;
  const int c0 = ublk + kg*4, c1 = c0 + 16;
  f32x4 acc0 = *(const f32x4*)&bih[c0];
  f32x4 acc1 = *(const f32x4*)&bih[c1];
  const int cc0 = c0 >= 384 ? c0 - 384 : c0;
  const int cc1 = c1 >= 384 ? c1 - 384 : c1;
  if ((cc0 >> 7) < 2) acc0 += *(const f32x4*)&bhhp[c0];
  if ((cc1 >> 7) < 2) acc1 += *(const f32x4*)&bhhp[c1];
  #pragma unroll
  for (int kc = 0; kc < 8; kc++){
    const s16x8 a  = *(const s16x8*)(Ap + kc*32);
    const s16x8 w0 = *(const s16x8*)(W0 + kc*32);
    const s16x8 w1 = *(const s16x8*)(W1 + kc*32);
    acc0 = mfma16(w0, a, acc0);   // A = weights (rows=units), B = activations
    acc1 = mfma16(w1, a, acc1);
  }
  const int f = f0 + l15, b = f >> 9, tt = f & 511;
  {
    const int d = c0 >= 384 ? 1 : 0;
    const int g = cc0 >> 7, u = cc0 & 127;
    *(f32x4*)&xw4[(((size_t)(d*3+g)*512 + tt)*32 + b)*128 + u] = acc0;
  }
  {
    const int d = c1 >= 384 ? 1 : 0;
    const int g = cc1 >> 7, u = cc1 & 127;
    *(f32x4*)&xw4[(((size_t)(d*3+g)*512 + tt)*32 + b)*128 + u] = acc1;
  }
}

// ---------------------------------------------------------------------------
// Weight prep (unchanged).
// ---------------------------------------------------------------------------
__global__ __launch_bounds__(256) void prep_kernel(
    const float* __restrict__ g0W, const float* __restrict__ g1W,
    const float* __restrict__ r1Wih,
    const float* __restrict__ r1bih, const float* __restrict__ r1bhh,
    u16* __restrict__ g0o, u16* __restrict__ g1o, u16* __restrict__ r1o,
    float* __restrict__ bo)
{
  const int i = blockIdx.x*256 + threadIdx.x;
  if (i < 196608){ g0o[i] = f2bf(g0W[i]); g1o[i] = f2bf(g1W[i]); }
  if (i < 32768)   r1o[i] = f2bf(r1Wih[32768 + i]);
  if (i < 128)     bo[i]  = r1bih[128+i] + r1bhh[128+i];
}

// ---------------------------------------------------------------------------
// GRU scan v7 = R8 v4 structure EXACTLY (the 305us configuration: direct
// per-lane fire-and-forget uint2 hout store, no post-barrier flush), with
// xw read from the plane layout via 3 marching pointers.
// ---------------------------------------------------------------------------
__global__ __launch_bounds__(512, 1) void gru_mfma(
    const float* __restrict__ xw4,  // (2,3,512,32,128) f32
    const float* __restrict__ Whh,  // (2,384,128) f32
    const float* __restrict__ bhh,  // (2,384)
    u16* __restrict__ hout)         // (16384,256) bf16
{
  __shared__ __align__(16) u16 h_lds[2][16][136];
  const int t = threadIdx.x;
  const int lane = t & 63, wv = t >> 6;
  const int l15 = lane & 15, kg = lane >> 4;
  const int dir = blockIdx.x & 1, half = blockIdx.x >> 1;
  // Whh A-fragments: row = g*128 + wv*16 + l15, k = kc*32 + kg*8
  s16x8 wa[3][4];
  {
    const float* Wd = Whh + (size_t)dir*49152;
    #pragma unroll
    for (int g = 0; g < 3; g++)
      #pragma unroll
      for (int kc = 0; kc < 4; kc++)
        wa[g][kc] = packfrag(&Wd[(size_t)(g*128 + wv*16 + l15)*128
                                 + kc*32 + kg*8]);
  }
  const f32x4 bhn = *(const f32x4*)&bhh[dir*384 + 256 + wv*16 + kg*4];
  if (t < 272) ((uint4*)h_lds)[t] = make_uint4(0,0,0,0);
  f32x4 hreg = {0.f,0.f,0.f,0.f};
  const int tt0 = dir ? 511 : 0;
  const long tstep = dir ? -16384L : 16384L;     // bytes per tt step (32*128*4)
  const size_t gplane = 512L*32*128*4;           // bytes per gate plane
  const char* xr = (const char*)xw4
      + ((((size_t)(dir*3)*512 + tt0)*32 + half*16 + l15)*128 + wv*16 + kg*4)*4;
  const char* xz = xr + gplane;
  const char* xn = xz + gplane;
  f32x4 pa[3], pb[3];
  pa[0] = *(const f32x4*)xr; pa[1] = *(const f32x4*)xz; pa[2] = *(const f32x4*)xn;
  xr += tstep; xz += tstep; xn += tstep;
  pb[0] = *(const f32x4*)xr; pb[1] = *(const f32x4*)xz; pb[2] = *(const f32x4*)xn;
  xr += tstep; xz += tstep; xn += tstep;
  const int hstep = dir ? -256 : 256;            // u16 units per tt step
  int hoff = ((half*16 + l15)*512 + tt0)*256 + dir*128 + wv*16 + kg*4;
  lds_barrier();
  int cur = 0;

#define GSTEP(PX, DOLOAD)                                                   \
  {                                                                         \
    f32x4 a0 = PX[0], a1 = PX[1], a2 = bhn;                                 \
    const f32x4 cxn = PX[2];                                                \
    if (DOLOAD){                                                            \
      PX[0] = *(const f32x4*)xr;                                            \
      PX[1] = *(const f32x4*)xz;                                            \
      PX[2] = *(const f32x4*)xn;                                            \
      xr += tstep; xz += tstep; xn += tstep;                                \
    }                                                                       \
    __builtin_amdgcn_s_setprio(1);                                          \
    _Pragma("unroll")                                                       \
    for (int kc = 0; kc < 4; kc++){                                         \
      const s16x8 hf = *(const s16x8*)&h_lds[cur][l15][kc*32 + kg*8];       \
      a0 = mfma16(wa[0][kc], hf, a0);                                       \
      a1 = mfma16(wa[1][kc], hf, a1);                                       \
      a2 = mfma16(wa[2][kc], hf, a2);                                       \
    }                                                                       \
    __builtin_amdgcn_s_setprio(0);                                          \
    float hn[4];                                                            \
    _Pragma("unroll")                                                       \
    for (int r = 0; r < 4; r++){                                            \
      const float rr = fast_sigmoid(a0[r]);                                 \
      const float zz = fast_sigmoid(a1[r]);                                 \
      const float nn = fast_tanh(fmaf(rr, a2[r], cxn[r]));                  \
      hn[r] = fmaf(zz, hreg[r] - nn, nn);                                   \
      hreg[r] = hn[r];                                                      \
    }                                                                       \
    const uint2 hp = make_uint2(cvt_pk_bf16(hn[0],hn[1]),                   \
                                cvt_pk_bf16(hn[2],hn[3]));                  \
    *(uint2*)&h_lds[cur^1][l15][wv*16 + kg*4] = hp;                         \
    *(uint2*)&hout[hoff] = hp;                                              \
    hoff += hstep;                                                          \
    lds_barrier();                                                          \
    cur ^= 1;                                                               \
  }

  for (int ti = 0; ti < 510; ti += 2){
    GSTEP(pa, 1);
    GSTEP(pb, 1);
  }
  GSTEP(pa, 0);   // step 510
  GSTEP(pb, 0);   // step 511
#undef GSTEP
}

__global__ void prefix_kernel(const int* __restrict__ lengths, int* __restrict__ pre){
  if (threadIdx.x == 0 && blockIdx.x == 0){
    int run = 0;
    for (int b = 0; b < 32; b++){ pre[b] = run; run += lengths[b]; }
  }
}

// ---------------------------------------------------------------------------
// Final FC (61 x 256) + ragged masked scatter into d_out (unchanged).
// ---------------------------------------------------------------------------
__global__ __launch_bounds__(256) void fc_kernel(
    const u16* __restrict__ A,      // (16384,256) bf16
    const float* __restrict__ W,    // (61,256)
    const float* __restrict__ bias, // (61)
    const int* __restrict__ lengths,
    const int* __restrict__ pre,
    float* __restrict__ out)
{
  __shared__ __align__(16) float4 Wl[64][61];
  __shared__ __align__(16) float  Al[64][256];
  const int t = threadIdx.x;
  const int row0 = blockIdx.x * 64;
  for (int idx = t; idx < 61*64; idx += 256){
    int c = idx >> 6, k4 = idx & 63;
    Wl[k4][c] = *(const float4*)&W[(size_t)c*256 + k4*4];
  }
  {
    const u32* A32 = (const u32*)(A + (size_t)row0*256);
    for (int idx = t; idx < 8192; idx += 256){
      u32 v = A32[idx];
      int r = idx >> 7, kp = idx & 127;
      Al[r][2*kp]   = bflo(v);
      Al[r][2*kp+1] = bfhi(v);
    }
  }
  __syncthreads();
  const int c = t & 63;
  const int rbase = t >> 6;
  if (c < 61){
    const float bv = bias[c];
    for (int rr = rbase; rr < 64; rr += 4){
      float s0=0,s1=0,s2=0,s3=0;
      const float4* Ap = (const float4*)&Al[rr][0];
      #pragma unroll
      for (int k4 = 0; k4 < 64; k4++){
        const float4 w = Wl[k4][c];
        const float4 a = Ap[k4];
        s0 = fmaf(w.x, a.x, s0);
        s1 = fmaf(w.y, a.y, s1);
        s2 = fmaf(w.z, a.z, s2);
        s3 = fmaf(w.w, a.w, s3);
      }
      const int n = row0 + rr;
      const int b = n >> 9, tt = n & 511;
      if (tt < lengths[b])
        out[(size_t)(pre[b] + tt)*61 + c] = bv + s0+s1+s2+s3;
    }
  }
}

extern "C" void kernel_launch(void* const* d_in, const int* in_sizes, int n_in,
                              void* d_out, int out_size, void* d_ws, size_t ws_size,
                              hipStream_t stream)
{
  const float* x     = (const float*)d_in[0];
  const int*   lens  = (const int*)d_in[1];
  const float* r0Wih = (const float*)d_in[2];
  const float* r0Whh = (const float*)d_in[3];
  const float* r0bih = (const float*)d_in[4];
  const float* r0bhh = (const float*)d_in[5];
  const float* r1Wih = (const float*)d_in[6];
  const float* r1Whh = (const float*)d_in[7];
  const float* r1bih = (const float*)d_in[8];
  const float* r1bhh = (const float*)d_in[9];
  const float* g0Wih = (const float*)d_in[10];
  const float* g0Whh = (const float*)d_in[11];
  const float* g0bih = (const float*)d_in[12];
  const float* g0bhh = (const float*)d_in[13];
  const float* g1Wih = (const float*)d_in[14];
  const float* g1Whh = (const float*)d_in[15];
  const float* g1bih = (const float*)d_in[16];
  const float* g1bhh = (const float*)d_in[17];
  const float* fcW   = (const float*)d_in[18];
  const float* fcb   = (const float*)d_in[19];
  float* out = (float*)d_out;

  char* ws = (char*)d_ws;
  u16*   l0buf = (u16*)(ws);
  float* xwbuf = (float*)(ws);                      // xw4 (2,3,512,32,128) f32
  u16*   g0out = (u16*)(ws + 50331648);
  u16*   g0Wb  = (u16*)(ws + 58720256);             // 393216 B
  u16*   g1Wb  = (u16*)(ws + 58720256 + 393216);    // 393216 B
  u16*   r1Wb  = (u16*)(ws + 58720256 + 786432);    // 65536 B
  float* biasb = (float*)(ws + 58720256 + 851968);  // 512 B
  u16*   g1out = (u16*)(ws + 58720256);             // overwrites prep late
  u16*   rnn1  = (u16*)(ws + 67108864);
  int*   pre   = (int*)(ws + 75497472);

  prep_kernel<<<768, 256, 0, stream>>>(g0Wih, g1Wih, r1Wih, r1bih, r1bhh,
                                       g0Wb, g1Wb, r1Wb, biasb);
  for (int c = 0; c < NF_/CH_; c++){
    l0_mfma<<<dim3(CH_/16, 2), 256, 0, stream>>>(
        x + (size_t)c*CH_*2048, r0Wih, r0Whh, r0bih, r0bhh, l0buf);
    l1f_mfma<<<dim3(CH_/16), 256, 0, stream>>>(
        l0buf, r1Wih, r1Whh, r1bih, r1bhh, r1Wb, biasb,
        rnn1 + (size_t)c*CH_*256);
  }
  // GRU layer 0
  gemm_xw<<<dim3(24, NF_/64), 256, 0, stream>>>(
      rnn1, g0Wb, g0bih, g0bhh, xwbuf);
  gru_mfma<<<4, 512, 0, stream>>>(xwbuf, g0Whh, g0bhh, g0out);
  // GRU layer 1
  gemm_xw<<<dim3(24, NF_/64), 256, 0, stream>>>(
      g0out, g1Wb, g1bih, g1bhh, xwbuf);
  gru_mfma<<<4, 512, 0, stream>>>(xwbuf, g1Whh, g1bhh, g1out);
  // FC + ragged scatter
  prefix_kernel<<<1, 64, 0, stream>>>(lens, pre);
  fc_kernel<<<NF_/64, 256, 0, stream>>>(g1out, fcW, fcb, lens, pre, out);
}

// Round 12
// 986.528 us; speedup vs baseline: 1.1884x; 1.1884x over previous
//
#include <hip/hip_runtime.h>
#include <hip/hip_bf16.h>

#define B_ 32
#define T_ 512
#define L_ 16
#define F_ 128
#define H_ 128
#define C_ 61
#define NF_ (B_*T_)   // 16384 frames
#define CH_ 4096      // frames per rnn1 chunk

typedef unsigned int u32;
typedef unsigned short u16;
typedef __attribute__((ext_vector_type(8))) short s16x8;
typedef __attribute__((ext_vector_type(4))) float f32x4;

__device__ __forceinline__ float bflo(u32 v){ return __uint_as_float(v << 16); }
__device__ __forceinline__ float bfhi(u32 v){ return __uint_as_float(v & 0xffff0000u); }
__device__ __forceinline__ u16 f2bf(float f){
  u32 u = __float_as_uint(f);
  u += 0x7fffu + ((u >> 16) & 1u);
  return (u16)(u >> 16);
}
__device__ __forceinline__ u32 pack2(float a, float b){
  return (u32)f2bf(a) | ((u32)f2bf(b) << 16);
}
__device__ __forceinline__ u32 cvt_pk_bf16(float a, float b){
  u32 d;
  asm("v_cvt_pk_bf16_f32 %0, %1, %2" : "=v"(d) : "v"(a), "v"(b));
  return d;
}
__device__ __forceinline__ float fast_tanh(float x){
  float e = __expf(2.f*x);
  return 1.f - 2.f*__builtin_amdgcn_rcpf(e + 1.f);
}
__device__ __forceinline__ float fast_sigmoid(float x){
  return __builtin_amdgcn_rcpf(1.f + __expf(-x));
}
__device__ __forceinline__ f32x4 mfma16(s16x8 a, s16x8 b, f32x4 c){
  return __builtin_amdgcn_mfma_f32_16x16x32_bf16(a, b, c, 0, 0, 0);
}
// LDS-only barrier: does NOT drain vmcnt (global prefetch loads / stores
// stay in flight), unlike __syncthreads which drains vmcnt(0).
__device__ __forceinline__ void lds_barrier(){
  asm volatile("s_waitcnt lgkmcnt(0)\n\ts_barrier" ::: "memory");
}
// pack 8 consecutive f32 (two float4) into a bf16x8 fragment, k-order
__device__ __forceinline__ s16x8 packfrag(const float* p){
  const float4 a = *(const float4*)p;
  const float4 b = *(const float4*)(p+4);
  union { s16x8 v; u32 w[4]; } f;
  f.w[0]=pack2(a.x,a.y); f.w[1]=pack2(a.z,a.w);
  f.w[2]=pack2(b.x,b.y); f.w[3]=pack2(b.z,b.w);
  return f.v;
}

// ---------------------------------------------------------------------------
// rnn1 layer 0 via MFMA. 16 frames/WG. Coalesced post-barrier LDS flush
// (kept from round 10).
// ---------------------------------------------------------------------------
__global__ __launch_bounds__(256) void l0_mfma(
    const float* __restrict__ x,      // (CH,16,128) chunk base
    const float* __restrict__ Wih,    // (2,128,128)
    const float* __restrict__ Whh,    // (2,128,128)
    const float* __restrict__ bih,    // (2,128)
    const float* __restrict__ bhh,    // (2,128)
    u16* __restrict__ out)            // (CH,16,256) bf16
{
  __shared__ __align__(16) u16 Hb[2][16][136];
  __shared__ __align__(16) u16 Xb[2][16][136];
  const int t = threadIdx.x;
  const int lane = t & 63, wv = t >> 6;
  const int l15 = lane & 15, kg = lane >> 4;
  const int dir = blockIdx.y;
  const int f0 = blockIdx.x * 16;
  s16x8 wih[2][4], whh[2][4];
  {
    const float* Wid = Wih + dir*16384;
    const float* Whd = Whh + dir*16384;
    #pragma unroll
    for (int nt = 0; nt < 2; nt++){
      const int u = wv*32 + nt*16 + l15;
      #pragma unroll
      for (int kc = 0; kc < 4; kc++){
        const int k = kc*32 + kg*8;
        wih[nt][kc] = packfrag(&Wid[u*128 + k]);
        whh[nt][kc] = packfrag(&Whd[u*128 + k]);
      }
    }
  }
  const float bv0 = bih[dir*128 + wv*32 + l15]      + bhh[dir*128 + wv*32 + l15];
  const float bv1 = bih[dir*128 + wv*32 + 16 + l15] + bhh[dir*128 + wv*32 + 16 + l15];
  const f32x4 bs0 = {bv0,bv0,bv0,bv0}, bs1 = {bv1,bv1,bv1,bv1};
  const int sr = t >> 4, sc8 = (t & 15) * 8;   // stage: frame row, col (8 f32)
  // flush role: frame ff, unit-block u8 (16 threads x 16B = one frame row)
  const int ff = t >> 4, u8 = (t & 15) * 8;
  u16* opbase = out + (size_t)f0*4096 + dir*128;
  int opoff = ff*4096 + (dir ? 15 : 0)*256 + u8;
  const int opstep = dir ? -256 : 256;
  for (int idx = t; idx < 272; idx += 256)
    ((uint4*)&Hb[0][0][0])[idx] = make_uint4(0,0,0,0);
  {
    const int s0 = dir ? 15 : 0;
    const float4* xp = (const float4*)&x[(size_t)(f0+sr)*2048 + s0*128 + sc8];
    const float4 v0 = xp[0], v1 = xp[1];
    *(uint4*)&Xb[0][sr][sc8] = make_uint4(pack2(v0.x,v0.y),pack2(v0.z,v0.w),
                                          pack2(v1.x,v1.y),pack2(v1.z,v1.w));
  }
  lds_barrier();
  int cur = 0;
  for (int st = 0; st < 16; st++){
    float4 p0,p1;
    if (st < 15){
      const int sn = dir ? (14-st) : (st+1);
      const float4* xp = (const float4*)&x[(size_t)(f0+sr)*2048 + sn*128 + sc8];
      p0 = xp[0]; p1 = xp[1];
    }
    f32x4 acc0 = bs0, acc1 = bs1;
    #pragma unroll
    for (int kc = 0; kc < 4; kc++){
      const int ko = kc*32 + kg*8;
      const s16x8 ax = *(const s16x8*)&Xb[cur][l15][ko];
      const s16x8 ah = *(const s16x8*)&Hb[cur][l15][ko];
      acc0 = mfma16(ax, wih[0][kc], acc0);
      acc1 = mfma16(ax, wih[1][kc], acc1);
      acc0 = mfma16(ah, whh[0][kc], acc0);
      acc1 = mfma16(ah, whh[1][kc], acc1);
    }
    const int u0 = wv*32 + l15, u1 = wv*32 + 16 + l15;
    #pragma unroll
    for (int r = 0; r < 4; r++){
      const int m = kg*4 + r;
      Hb[cur^1][m][u0] = f2bf(fast_tanh(acc0[r]));
      Hb[cur^1][m][u1] = f2bf(fast_tanh(acc1[r]));
    }
    if (st < 15){
      *(uint4*)&Xb[cur^1][sr][sc8] = make_uint4(pack2(p0.x,p0.y),pack2(p0.z,p0.w),
                                                pack2(p1.x,p1.y),pack2(p1.z,p1.w));
    }
    lds_barrier();
    // coalesced flush of this step's h (reads the buffer just written)
    {
      const uint4 hv = *(const uint4*)&Hb[cur^1][ff][u8];
      *(uint4*)&opbase[opoff] = hv;
      opoff += opstep;
    }
    cur ^= 1;
  }
}

// ---------------------------------------------------------------------------
// rnn1 layer 1 FORWARD via MFMA, 16 frames/WG + FUSED l1-backward single-step
// GEMM at st==15 (kept from round 10).
// ---------------------------------------------------------------------------
__global__ __launch_bounds__(256) void l1f_mfma(
    const u16* __restrict__ U,        // (CH,16,256) bf16
    const float* __restrict__ Wih,    // (2,128,256) dir0
    const float* __restrict__ Whh,    // (2,128,128) dir0
    const float* __restrict__ bih,    // (2,128)
    const float* __restrict__ bhh,
    const u16* __restrict__ r1Wb,     // (128,256) bf16 = dir1 Wih
    const float* __restrict__ biasb,  // (128) dir1 bih+bhh
    u16* __restrict__ out)            // rnn1 rows (ld 256)
{
  __shared__ __align__(16) u16 Hb[2][16][136];
  __shared__ __align__(16) u16 Xb[2][16][264];
  const int t = threadIdx.x;
  const int lane = t & 63, wv = t >> 6;
  const int l15 = lane & 15, kg = lane >> 4;
  const int f0 = blockIdx.x * 16;
  s16x8 wih[2][8], whh[2][4];
  {
    #pragma unroll
    for (int nt = 0; nt < 2; nt++){
      const int u = wv*32 + nt*16 + l15;
      #pragma unroll
      for (int kc = 0; kc < 8; kc++)
        wih[nt][kc] = packfrag(&Wih[u*256 + kc*32 + kg*8]);
      #pragma unroll
      for (int kc = 0; kc < 4; kc++)
        whh[nt][kc] = packfrag(&Whh[u*128 + kc*32 + kg*8]);
    }
  }
  const float bv0 = bih[wv*32 + l15]      + bhh[wv*32 + l15];
  const float bv1 = bih[wv*32 + 16 + l15] + bhh[wv*32 + 16 + l15];
  const f32x4 bs0 = {bv0,bv0,bv0,bv0}, bs1 = {bv1,bv1,bv1,bv1};
  const int sr = t >> 4, scu = (t & 15) * 16;
  for (int idx = t; idx < 272; idx += 256)
    ((uint4*)&Hb[0][0][0])[idx] = make_uint4(0,0,0,0);
  {
    const uint4* up = (const uint4*)&U[(size_t)(f0+sr)*4096 + scu];
    uint4 c0 = up[0], c1 = up[1];
    *(uint4*)&Xb[0][sr][scu]   = c0;
    *(uint4*)&Xb[0][sr][scu+8] = c1;
  }
  lds_barrier();
  int cur = 0;
  for (int st = 0; st < 16; st++){
    uint4 c0,c1;
    if (st < 15){
      const uint4* up = (const uint4*)&U[(size_t)(f0+sr)*4096 + (st+1)*256 + scu];
      c0 = up[0]; c1 = up[1];
    }
    f32x4 acc0 = bs0, acc1 = bs1;
    #pragma unroll
    for (int kc = 0; kc < 8; kc++){
      const s16x8 ax = *(const s16x8*)&Xb[cur][l15][kc*32 + kg*8];
      acc0 = mfma16(ax, wih[0][kc], acc0);
      acc1 = mfma16(ax, wih[1][kc], acc1);
    }
    #pragma unroll
    for (int kc = 0; kc < 4; kc++){
      const s16x8 ah = *(const s16x8*)&Hb[cur][l15][kc*32 + kg*8];
      acc0 = mfma16(ah, whh[0][kc], acc0);
      acc1 = mfma16(ah, whh[1][kc], acc1);
    }
    const int u0 = wv*32 + l15, u1 = wv*32 + 16 + l15;
    #pragma unroll
    for (int r = 0; r < 4; r++){
      const int m = kg*4 + r;
      const u16 h0 = f2bf(fast_tanh(acc0[r]));
      const u16 h1 = f2bf(fast_tanh(acc1[r]));
      Hb[cur^1][m][u0] = h0;
      Hb[cur^1][m][u1] = h1;
      if (st == 15){
        out[(size_t)(f0+m)*256 + u0] = h0;
        out[(size_t)(f0+m)*256 + u1] = h1;
      }
    }
    if (st == 15){
      // fused l1-backward @ s=15: tanh(U15 @ Wihb^T + biasb), cols 128..255
      const float bb0 = biasb[wv*32 + l15];
      const float bb1 = biasb[wv*32 + 16 + l15];
      f32x4 ab0 = {bb0,bb0,bb0,bb0}, ab1 = {bb1,bb1,bb1,bb1};
      #pragma unroll
      for (int kc = 0; kc < 8; kc++){
        const s16x8 uf = *(const s16x8*)&Xb[cur][l15][kc*32 + kg*8];
        const s16x8 w0 = *(const s16x8*)&r1Wb[(size_t)(wv*32 + l15)*256 + kc*32 + kg*8];
        const s16x8 w1 = *(const s16x8*)&r1Wb[(size_t)(wv*32 + 16 + l15)*256 + kc*32 + kg*8];
        ab0 = mfma16(uf, w0, ab0);
        ab1 = mfma16(uf, w1, ab1);
      }
      #pragma unroll
      for (int r = 0; r < 4; r++){
        const int m = kg*4 + r;
        out[(size_t)(f0+m)*256 + 128 + wv*32 + l15]      = f2bf(fast_tanh(ab0[r]));
        out[(size_t)(f0+m)*256 + 128 + wv*32 + 16 + l15] = f2bf(fast_tanh(ab1[r]));
      }
    }
    if (st < 15){
      *(uint4*)&Xb[cur^1][sr][scu]   = c0;
      *(uint4*)&Xb[cur^1][sr][scu+8] = c1;
    }
    lds_barrier();
    cur ^= 1;
  }
}

// ---------------------------------------------------------------------------
// xw GEMM, operand-swapped (weights = A, rows = units), writing the gru v3
// layout with 16B stores: per (d,tt,half) block of 6144 floats, gru lane
// (wv,kg,l15) owns 12 contiguous floats at ((wv*4+kg)*16+l15)*12, ordered
// [r x4][z x4][n x4] over its 4 consecutive units. Each gemm lane's f32x4
// (4 consecutive units, one gate, one frame) -> one 16B store.
// bih (+ bhh for r,z gates) folded via the MFMA C-operand.
// ---------------------------------------------------------------------------
__global__ __launch_bounds__(256) void gemm_xw(
    const u16* __restrict__ A,       // (16384,256) bf16 activations
    const u16* __restrict__ Wb,      // (768,256) bf16 weights
    const float* __restrict__ bih,   // (768)
    const float* __restrict__ bhhp,  // (768)
    float* __restrict__ xwT)         // (2,512,2,6144) f32, gru-native v3
{
  const int t = threadIdx.x;
  const int lane = t & 63, wv = t >> 6;
  const int l15 = lane & 15, kg = lane >> 4;
  const int ublk = blockIdx.x * 32;              // unit-block (24 blocks)
  const int f0 = blockIdx.y * 64 + wv*16;        // frame-block, 16/wave
  const u16* Ap = A  + (size_t)(f0 + l15)*256 + kg*8;
  const u16* W0 = Wb + (size_t)(ublk + l15)*256 + kg*8;
  const u16* W1 = Wb + (size_t)(ublk + 16 + l15)*256 + kg*8;
  const int c0 = ublk + kg*4, c1 = c0 + 16;
  f32x4 acc0 = *(const f32x4*)&bih[c0];
  f32x4 acc1 = *(const f32x4*)&bih[c1];
  const int cc0 = c0 >= 384 ? c0 - 384 : c0;
  const int cc1 = c1 >= 384 ? c1 - 384 : c1;
  if ((cc0 >> 7) < 2) acc0 += *(const f32x4*)&bhhp[c0];
  if ((cc1 >> 7) < 2) acc1 += *(const f32x4*)&bhhp[c1];
  #pragma unroll
  for (int kc = 0; kc < 8; kc++){
    const s16x8 a  = *(const s16x8*)(Ap + kc*32);
    const s16x8 w0 = *(const s16x8*)(W0 + kc*32);
    const s16x8 w1 = *(const s16x8*)(W1 + kc*32);
    acc0 = mfma16(w0, a, acc0);   // D rows = units, cols = frames
    acc1 = mfma16(w1, a, acc1);
  }
  const int f = f0 + l15, b = f >> 9, tt = f & 511;
  const int half = b >> 4, bl = b & 15;
  {
    const int d = c0 >= 384 ? 1 : 0;
    const int g = cc0 >> 7, u = cc0 & 127;
    const size_t idx = (((size_t)d*512 + tt)*2 + half)*6144
        + (size_t)(((u>>4)*4 + ((u>>2)&3))*16 + bl)*12 + g*4;
    *(f32x4*)&xwT[idx] = acc0;
  }
  {
    const int d = c1 >= 384 ? 1 : 0;
    const int g = cc1 >> 7, u = cc1 & 127;
    const size_t idx = (((size_t)d*512 + tt)*2 + half)*6144
        + (size_t)(((u>>4)*4 + ((u>>2)&3))*16 + bl)*12 + g*4;
    *(f32x4*)&xwT[idx] = acc1;
  }
}

// ---------------------------------------------------------------------------
// Weight prep (unchanged).
// ---------------------------------------------------------------------------
__global__ __launch_bounds__(256) void prep_kernel(
    const float* __restrict__ g0W, const float* __restrict__ g1W,
    const float* __restrict__ r1Wih,
    const float* __restrict__ r1bih, const float* __restrict__ r1bhh,
    u16* __restrict__ g0o, u16* __restrict__ g1o, u16* __restrict__ r1o,
    float* __restrict__ bo)
{
  const int i = blockIdx.x*256 + threadIdx.x;
  if (i < 196608){ g0o[i] = f2bf(g0W[i]); g1o[i] = f2bf(g1W[i]); }
  if (i < 32768)   r1o[i] = f2bf(r1Wih[32768 + i]);
  if (i < 128)     bo[i]  = r1bih[128+i] + r1bhh[128+i];
}

// ---------------------------------------------------------------------------
// GRU scan: EXACT round-8 v4 structure (measured 305us): v3 xw layout read
// via ONE marching pointer (48B contiguous per lane, 3KB contiguous per
// wave), per-lane fire-and-forget uint2 hout store, acc-init from xw,
// cvt_pk packing, setprio around MFMA, LDS-only barriers.
// ---------------------------------------------------------------------------
__global__ __launch_bounds__(512, 1) void gru_mfma(
    const float* __restrict__ xwT,  // (2,512,2,6144) gru-native v3
    const float* __restrict__ Whh,  // (2,384,128) f32
    const float* __restrict__ bhh,  // (2,384)
    u16* __restrict__ hout)         // (16384,256) bf16
{
  __shared__ __align__(16) u16 h_lds[2][16][136];
  const int t = threadIdx.x;
  const int lane = t & 63, wv = t >> 6;
  const int l15 = lane & 15, kg = lane >> 4;
  const int dir = blockIdx.x & 1, half = blockIdx.x >> 1;
  // Whh A-fragments: row = g*128 + wv*16 + l15, k = kc*32 + kg*8
  s16x8 wa[3][4];
  {
    const float* Wd = Whh + (size_t)dir*49152;
    #pragma unroll
    for (int g = 0; g < 3; g++)
      #pragma unroll
      for (int kc = 0; kc < 4; kc++)
        wa[g][kc] = packfrag(&Wd[(size_t)(g*128 + wv*16 + l15)*128
                                 + kc*32 + kg*8]);
  }
  const f32x4 bhn = *(const f32x4*)&bhh[dir*384 + 256 + wv*16 + kg*4];
  if (t < 272) ((uint4*)h_lds)[t] = make_uint4(0,0,0,0);
  f32x4 hreg = {0.f,0.f,0.f,0.f};
  const long tstep = dir ? -49152L : 49152L;     // bytes per tt step
  const char* xb = (const char*)xwT
      + (((size_t)dir*512 + (dir ? 511 : 0))*2 + half)*24576
      + (size_t)(((wv*4 + kg)*16 + l15)*12)*4;
  f32x4 pa[3], pb[3];
  pa[0] = *(const f32x4*)(xb); pa[1] = *(const f32x4*)(xb+16); pa[2] = *(const f32x4*)(xb+32);
  xb += tstep;
  pb[0] = *(const f32x4*)(xb); pb[1] = *(const f32x4*)(xb+16); pb[2] = *(const f32x4*)(xb+32);
  xb += tstep;
  const int hstep = dir ? -256 : 256;            // u16 units per tt step
  int hoff = ((half*16 + l15)*512 + (dir ? 511 : 0))*256 + dir*128 + wv*16 + kg*4;
  lds_barrier();
  int cur = 0;

#define GSTEP(PX, DOLOAD)                                                   \
  {                                                                         \
    f32x4 a0 = PX[0], a1 = PX[1], a2 = bhn;                                 \
    const f32x4 cxn = PX[2];                                                \
    if (DOLOAD){                                                            \
      PX[0] = *(const f32x4*)(xb);                                          \
      PX[1] = *(const f32x4*)(xb+16);                                       \
      PX[2] = *(const f32x4*)(xb+32);                                       \
      xb += tstep;                                                          \
    }                                                                       \
    __builtin_amdgcn_s_setprio(1);                                          \
    _Pragma("unroll")                                                       \
    for (int kc = 0; kc < 4; kc++){                                         \
      const s16x8 hf = *(const s16x8*)&h_lds[cur][l15][kc*32 + kg*8];       \
      a0 = mfma16(wa[0][kc], hf, a0);                                       \
      a1 = mfma16(wa[1][kc], hf, a1);                                       \
      a2 = mfma16(wa[2][kc], hf, a2);                                       \
    }                                                                       \
    __builtin_amdgcn_s_setprio(0);                                          \
    float hn[4];                                                            \
    _Pragma("unroll")                                                       \
    for (int r = 0; r < 4; r++){                                            \
      const float rr = fast_sigmoid(a0[r]);                                 \
      const float zz = fast_sigmoid(a1[r]);                                 \
      const float nn = fast_tanh(fmaf(rr, a2[r], cxn[r]));                  \
      hn[r] = fmaf(zz, hreg[r] - nn, nn);                                   \
      hreg[r] = hn[r];                                                      \
    }                                                                       \
    const uint2 hp = make_uint2(cvt_pk_bf16(hn[0],hn[1]),                   \
                                cvt_pk_bf16(hn[2],hn[3]));                  \
    *(uint2*)&h_lds[cur^1][l15][wv*16 + kg*4] = hp;                         \
    *(uint2*)&hout[hoff] = hp;                                              \
    hoff += hstep;                                                          \
    lds_barrier();                                                          \
    cur ^= 1;                                                               \
  }

  for (int ti = 0; ti < 510; ti += 2){
    GSTEP(pa, 1);
    GSTEP(pb, 1);
  }
  GSTEP(pa, 0);   // step 510
  GSTEP(pb, 0);   // step 511
#undef GSTEP
}

__global__ void prefix_kernel(const int* __restrict__ lengths, int* __restrict__ pre){
  if (threadIdx.x == 0 && blockIdx.x == 0){
    int run = 0;
    for (int b = 0; b < 32; b++){ pre[b] = run; run += lengths[b]; }
  }
}

// ---------------------------------------------------------------------------
// Final FC (61 x 256) + ragged masked scatter into d_out (unchanged).
// ---------------------------------------------------------------------------
__global__ __launch_bounds__(256) void fc_kernel(
    const u16* __restrict__ A,      // (16384,256) bf16
    const float* __restrict__ W,    // (61,256)
    const float* __restrict__ bias, // (61)
    const int* __restrict__ lengths,
    const int* __restrict__ pre,
    float* __restrict__ out)
{
  __shared__ __align__(16) float4 Wl[64][61];
  __shared__ __align__(16) float  Al[64][256];
  const int t = threadIdx.x;
  const int row0 = blockIdx.x * 64;
  for (int idx = t; idx < 61*64; idx += 256){
    int c = idx >> 6, k4 = idx & 63;
    Wl[k4][c] = *(const float4*)&W[(size_t)c*256 + k4*4];
  }
  {
    const u32* A32 = (const u32*)(A + (size_t)row0*256);
    for (int idx = t; idx < 8192; idx += 256){
      u32 v = A32[idx];
      int r = idx >> 7, kp = idx & 127;
      Al[r][2*kp]   = bflo(v);
      Al[r][2*kp+1] = bfhi(v);
    }
  }
  __syncthreads();
  const int c = t & 63;
  const int rbase = t >> 6;
  if (c < 61){
    const float bv = bias[c];
    for (int rr = rbase; rr < 64; rr += 4){
      float s0=0,s1=0,s2=0,s3=0;
      const float4* Ap = (const float4*)&Al[rr][0];
      #pragma unroll
      for (int k4 = 0; k4 < 64; k4++){
        const float4 w = Wl[k4][c];
        const float4 a = Ap[k4];
        s0 = fmaf(w.x, a.x, s0);
        s1 = fmaf(w.y, a.y, s1);
        s2 = fmaf(w.z, a.z, s2);
        s3 = fmaf(w.w, a.w, s3);
      }
      const int n = row0 + rr;
      const int b = n >> 9, tt = n & 511;
      if (tt < lengths[b])
        out[(size_t)(pre[b] + tt)*61 + c] = bv + s0+s1+s2+s3;
    }
  }
}

extern "C" void kernel_launch(void* const* d_in, const int* in_sizes, int n_in,
                              void* d_out, int out_size, void* d_ws, size_t ws_size,
                              hipStream_t stream)
{
  const float* x     = (const float*)d_in[0];
  const int*   lens  = (const int*)d_in[1];
  const float* r0Wih = (const float*)d_in[2];
  const float* r0Whh = (const float*)d_in[3];
  const float* r0bih = (const float*)d_in[4];
  const float* r0bhh = (const float*)d_in[5];
  const float* r1Wih = (const float*)d_in[6];
  const float* r1Whh = (const float*)d_in[7];
  const float* r1bih = (const float*)d_in[8];
  const float* r1bhh = (const float*)d_in[9];
  const float* g0Wih = (const float*)d_in[10];
  const float* g0Whh = (const float*)d_in[11];
  const float* g0bih = (const float*)d_in[12];
  const float* g0bhh = (const float*)d_in[13];
  const float* g1Wih = (const float*)d_in[14];
  const float* g1Whh = (const float*)d_in[15];
  const float* g1bih = (const float*)d_in[16];
  const float* g1bhh = (const float*)d_in[17];
  const float* fcW   = (const float*)d_in[18];
  const float* fcb   = (const float*)d_in[19];
  float* out = (float*)d_out;

  char* ws = (char*)d_ws;
  u16*   l0buf = (u16*)(ws);
  float* xwbuf = (float*)(ws);                      // xwT (2,512,2,6144) f32
  u16*   g0out = (u16*)(ws + 50331648);
  u16*   g0Wb  = (u16*)(ws + 58720256);             // 393216 B
  u16*   g1Wb  = (u16*)(ws + 58720256 + 393216);    // 393216 B
  u16*   r1Wb  = (u16*)(ws + 58720256 + 786432);    // 65536 B
  float* biasb = (float*)(ws + 58720256 + 851968);  // 512 B
  u16*   g1out = (u16*)(ws + 58720256);             // overwrites prep late
  u16*   rnn1  = (u16*)(ws + 67108864);
  int*   pre   = (int*)(ws + 75497472);

  prep_kernel<<<768, 256, 0, stream>>>(g0Wih, g1Wih, r1Wih, r1bih, r1bhh,
                                       g0Wb, g1Wb, r1Wb, biasb);
  for (int c = 0; c < NF_/CH_; c++){
    l0_mfma<<<dim3(CH_/16, 2), 256, 0, stream>>>(
        x + (size_t)c*CH_*2048, r0Wih, r0Whh, r0bih, r0bhh, l0buf);
    l1f_mfma<<<dim3(CH_/16), 256, 0, stream>>>(
        l0buf, r1Wih, r1Whh, r1bih, r1bhh, r1Wb, biasb,
        rnn1 + (size_t)c*CH_*256);
  }
  // GRU layer 0
  gemm_xw<<<dim3(24, NF_/64), 256, 0, stream>>>(
      rnn1, g0Wb, g0bih, g0bhh, xwbuf);
  gru_mfma<<<4, 512, 0, stream>>>(xwbuf, g0Whh, g0bhh, g0out);
  // GRU layer 1
  gemm_xw<<<dim3(24, NF_/64), 256, 0, stream>>>(
      g0out, g1Wb, g1bih, g1bhh, xwbuf);
  gru_mfma<<<4, 512, 0, stream>>>(xwbuf, g1Whh, g1bhh, g1out);
  // FC + ragged scatter
  prefix_kernel<<<1, 64, 0, stream>>>(lens, pre);
  fc_kernel<<<NF_/64, 256, 0, stream>>>(g1out, fcW, fcb, lens, pre, out);
}

// Round 14
// 970.035 us; speedup vs baseline: 1.2086x; 1.0170x over previous
//
#include <hip/hip_runtime.h>
#include <hip/hip_bf16.h>

#define B_ 32
#define T_ 512
#define L_ 16
#define F_ 128
#define H_ 128
#define C_ 61
#define NF_ (B_*T_)   // 16384 frames

typedef unsigned int u32;
typedef unsigned short u16;
typedef __attribute__((ext_vector_type(8))) short s16x8;
typedef __attribute__((ext_vector_type(4))) float f32x4;

__device__ __forceinline__ float bflo(u32 v){ return __uint_as_float(v << 16); }
__device__ __forceinline__ float bfhi(u32 v){ return __uint_as_float(v & 0xffff0000u); }
__device__ __forceinline__ u16 f2bf(float f){
  u32 u = __float_as_uint(f);
  u += 0x7fffu + ((u >> 16) & 1u);
  return (u16)(u >> 16);
}
__device__ __forceinline__ u32 pack2(float a, float b){
  return (u32)f2bf(a) | ((u32)f2bf(b) << 16);
}
__device__ __forceinline__ u32 cvt_pk_bf16(float a, float b){
  u32 d;
  asm("v_cvt_pk_bf16_f32 %0, %1, %2" : "=v"(d) : "v"(a), "v"(b));
  return d;
}
__device__ __forceinline__ float fast_tanh(float x){
  float e = __expf(2.f*x);
  return 1.f - 2.f*__builtin_amdgcn_rcpf(e + 1.f);
}
__device__ __forceinline__ float fast_sigmoid(float x){
  return __builtin_amdgcn_rcpf(1.f + __expf(-x));
}
__device__ __forceinline__ f32x4 mfma16(s16x8 a, s16x8 b, f32x4 c){
  return __builtin_amdgcn_mfma_f32_16x16x32_bf16(a, b, c, 0, 0, 0);
}
// LDS-only barrier: does NOT drain vmcnt (global prefetch loads / stores
// stay in flight), unlike __syncthreads which drains vmcnt(0).
__device__ __forceinline__ void lds_barrier(){
  asm volatile("s_waitcnt lgkmcnt(0)\n\ts_barrier" ::: "memory");
}
// pack 8 consecutive f32 (two float4) into a bf16x8 fragment, k-order
__device__ __forceinline__ s16x8 packfrag(const float* p){
  const float4 a = *(const float4*)p;
  const float4 b = *(const float4*)(p+4);
  union { s16x8 v; u32 w[4]; } f;
  f.w[0]=pack2(a.x,a.y); f.w[1]=pack2(a.z,a.w);
  f.w[2]=pack2(b.x,b.y); f.w[3]=pack2(b.z,b.w);
  return f.v;
}

// ---------------------------------------------------------------------------
// FUSED rnn1: one WG = 16 frames, 256 thr (4 waves), entire l0 output in LDS.
// Phase 1: dir1 l0 scan (s=15..0) -> U1[s] LDS; also packs x -> XA LDS cache.
// Phase 2: dir0 l0 + l1f forward pipelined per step; fused l1-backward
// single-step GEMM at s=15. Eliminates the 268MB l0buf HBM round-trip.
// LDS = 2x 69.6KB (U1, XA; pad 136 -> 272B rows, 16B-aligned for b128)
//       + 2x 8.7KB (Hb0, Hb1) = 156.7 KB (< 160 KB).
// ---------------------------------------------------------------------------
__global__ __launch_bounds__(256, 1) void rnn1_fused(
    const float* __restrict__ x,      // (NF,16,128)
    const float* __restrict__ Wih,    // (2,128,128) l0
    const float* __restrict__ Whh,    // (2,128,128) l0
    const float* __restrict__ bih,    // (2,128) l0
    const float* __restrict__ bhh,    // (2,128) l0
    const float* __restrict__ Wih1,   // (2,128,256) l1 (dir0 used here)
    const float* __restrict__ Whh1,   // (2,128,128) l1 dir0
    const float* __restrict__ bih1,   // (2,128)
    const float* __restrict__ bhh1,
    const u16*  __restrict__ r1Wb,    // (128,256) bf16 = l1 dir1 Wih
    const float* __restrict__ biasb,  // (128) l1 dir1 bih+bhh
    u16* __restrict__ out)            // rnn1 (NF,256)
{
  __shared__ __align__(16) u16 U1[16][16][136];   // dir1 l0 out  [s][frame][unit]
  __shared__ __align__(16) u16 XA[16][16][136];   // x bf16 cache [s][frame][feat]
  __shared__ __align__(16) u16 Hb0[2][16][136];   // dir0 l0 h dbuf
  __shared__ __align__(16) u16 Hb1[2][16][136];   // l1 fwd h dbuf
  const int t = threadIdx.x;
  const int lane = t & 63, wv = t >> 6;
  const int l15 = lane & 15, kg = lane >> 4;
  const int f0 = blockIdx.x * 16;
  const int sr = t >> 4, sc8 = (t & 15) * 8;      // staging: frame row, 8-f32 col
  const int u0 = wv*32 + l15, u1 = wv*32 + 16 + l15;

  // ---- init: zero h buffers (buffer 0 = 272 uint4 each), stage XA[15] ----
  {
    const uint4 z = make_uint4(0,0,0,0);
    for (int idx = t; idx < 272; idx += 256){
      ((uint4*)&Hb0[0][0][0])[idx] = z;
      ((uint4*)&Hb1[0][0][0])[idx] = z;
    }
    const float4* xp = (const float4*)&x[(size_t)(f0+sr)*2048 + 15*128 + sc8];
    const float4 v0 = xp[0], v1 = xp[1];
    *(uint4*)&XA[15][sr][sc8] = make_uint4(pack2(v0.x,v0.y),pack2(v0.z,v0.w),
                                           pack2(v1.x,v1.y),pack2(v1.z,v1.w));
  }

  // ======== PHASE 1: dir1 l0 scan, store to U1, stage XA ========
  {
    s16x8 wihd[2][4], whhd[2][4];
    #pragma unroll
    for (int nt = 0; nt < 2; nt++){
      const int u = wv*32 + nt*16 + l15;
      #pragma unroll
      for (int kc = 0; kc < 4; kc++){
        const int k = kc*32 + kg*8;
        wihd[nt][kc] = packfrag(&Wih[16384 + u*128 + k]);
        whhd[nt][kc] = packfrag(&Whh[16384 + u*128 + k]);
      }
    }
    const float bv0 = bih[128 + u0] + bhh[128 + u0];
    const float bv1 = bih[128 + u1] + bhh[128 + u1];
    const f32x4 bs0 = {bv0,bv0,bv0,bv0}, bs1 = {bv1,bv1,bv1,bv1};
    lds_barrier();
    for (int st = 0; st < 16; st++){
      const int s = 15 - st;
      float4 p0, p1;
      if (s > 0){
        const float4* xp = (const float4*)&x[(size_t)(f0+sr)*2048 + (s-1)*128 + sc8];
        p0 = xp[0]; p1 = xp[1];
      }
      f32x4 acc0 = bs0, acc1 = bs1;
      #pragma unroll
      for (int kc = 0; kc < 4; kc++){
        const int ko = kc*32 + kg*8;
        const s16x8 ax = *(const s16x8*)&XA[s][l15][ko];
        acc0 = mfma16(ax, wihd[0][kc], acc0);
        acc1 = mfma16(ax, wihd[1][kc], acc1);
      }
      if (st > 0){
        #pragma unroll
        for (int kc = 0; kc < 4; kc++){
          const int ko = kc*32 + kg*8;
          const s16x8 ah = *(const s16x8*)&U1[s+1][l15][ko];
          acc0 = mfma16(ah, whhd[0][kc], acc0);
          acc1 = mfma16(ah, whhd[1][kc], acc1);
        }
      }
      #pragma unroll
      for (int r = 0; r < 4; r++){
        const int m = kg*4 + r;
        U1[s][m][u0] = f2bf(fast_tanh(acc0[r]));
        U1[s][m][u1] = f2bf(fast_tanh(acc1[r]));
      }
      if (s > 0){
        *(uint4*)&XA[s-1][sr][sc8] = make_uint4(pack2(p0.x,p0.y),pack2(p0.z,p0.w),
                                                pack2(p1.x,p1.y),pack2(p1.z,p1.w));
      }
      lds_barrier();
    }
  }

  // ======== PHASE 2: dir0 l0 + l1f forward, pipelined per step ========
  {
    s16x8 wih0[2][4], whh0[2][4];
    s16x8 w1ih[2][8], w1hh[2][4];
    #pragma unroll
    for (int nt = 0; nt < 2; nt++){
      const int u = wv*32 + nt*16 + l15;
      #pragma unroll
      for (int kc = 0; kc < 4; kc++){
        const int k = kc*32 + kg*8;
        wih0[nt][kc] = packfrag(&Wih[u*128 + k]);
        whh0[nt][kc] = packfrag(&Whh[u*128 + k]);
        w1hh[nt][kc] = packfrag(&Whh1[u*128 + k]);
      }
      #pragma unroll
      for (int kc = 0; kc < 8; kc++)
        w1ih[nt][kc] = packfrag(&Wih1[u*256 + kc*32 + kg*8]);
    }
    const float a_bv0 = bih[u0] + bhh[u0];
    const float a_bv1 = bih[u1] + bhh[u1];
    const float l_bv0 = bih1[u0] + bhh1[u0];
    const float l_bv1 = bih1[u1] + bhh1[u1];
    const f32x4 abs0 = {a_bv0,a_bv0,a_bv0,a_bv0}, abs1 = {a_bv1,a_bv1,a_bv1,a_bv1};
    const f32x4 lbs0 = {l_bv0,l_bv0,l_bv0,l_bv0}, lbs1 = {l_bv1,l_bv1,l_bv1,l_bv1};
    int cur = 0;
    for (int s = 0; s < 16; s++){
      // --- l0 dir0 step ---
      f32x4 a0 = abs0, a1 = abs1;
      #pragma unroll
      for (int kc = 0; kc < 4; kc++){
        const int ko = kc*32 + kg*8;
        const s16x8 ax = *(const s16x8*)&XA[s][l15][ko];
        const s16x8 ah = *(const s16x8*)&Hb0[cur][l15][ko];
        a0 = mfma16(ax, wih0[0][kc], a0);
        a1 = mfma16(ax, wih0[1][kc], a1);
        a0 = mfma16(ah, whh0[0][kc], a0);
        a1 = mfma16(ah, whh0[1][kc], a1);
      }
      #pragma unroll
      for (int r = 0; r < 4; r++){
        const int m = kg*4 + r;
        Hb0[cur^1][m][u0] = f2bf(fast_tanh(a0[r]));
        Hb0[cur^1][m][u1] = f2bf(fast_tanh(a1[r]));
      }
      lds_barrier();
      // --- l1f step: ih over [h0(s) | U1[s]], hh over Hb1 ---
      f32x4 b0 = lbs0, b1 = lbs1;
      #pragma unroll
      for (int kc = 0; kc < 4; kc++){
        const int ko = kc*32 + kg*8;
        const s16x8 af = *(const s16x8*)&Hb0[cur^1][l15][ko];
        b0 = mfma16(af, w1ih[0][kc], b0);
        b1 = mfma16(af, w1ih[1][kc], b1);
      }
      #pragma unroll
      for (int kc = 4; kc < 8; kc++){
        const int ko = (kc-4)*32 + kg*8;
        const s16x8 af = *(const s16x8*)&U1[s][l15][ko];
        b0 = mfma16(af, w1ih[0][kc], b0);
        b1 = mfma16(af, w1ih[1][kc], b1);
      }
      #pragma unroll
      for (int kc = 0; kc < 4; kc++){
        const int ko = kc*32 + kg*8;
        const s16x8 ah = *(const s16x8*)&Hb1[cur][l15][ko];
        b0 = mfma16(ah, w1hh[0][kc], b0);
        b1 = mfma16(ah, w1hh[1][kc], b1);
      }
      #pragma unroll
      for (int r = 0; r < 4; r++){
        const int m = kg*4 + r;
        const u16 h0 = f2bf(fast_tanh(b0[r]));
        const u16 h1 = f2bf(fast_tanh(b1[r]));
        Hb1[cur^1][m][u0] = h0;
        Hb1[cur^1][m][u1] = h1;
        if (s == 15){
          out[(size_t)(f0+m)*256 + u0] = h0;
          out[(size_t)(f0+m)*256 + u1] = h1;
        }
      }
      if (s == 15){
        // fused l1-backward @ s=15: tanh(U(15) @ Wihb^T + biasb), cols 128..255
        const float bb0 = biasb[u0], bb1 = biasb[u1];
        f32x4 c0 = {bb0,bb0,bb0,bb0}, c1 = {bb1,bb1,bb1,bb1};
        #pragma unroll
        for (int kc = 0; kc < 4; kc++){
          const int ko = kc*32 + kg*8;
          const s16x8 af = *(const s16x8*)&Hb0[cur^1][l15][ko];
          const s16x8 w0 = *(const s16x8*)&r1Wb[(size_t)u0*256 + ko];
          const s16x8 w1 = *(const s16x8*)&r1Wb[(size_t)u1*256 + ko];
          c0 = mfma16(af, w0, c0);
          c1 = mfma16(af, w1, c1);
        }
        #pragma unroll
        for (int kc = 4; kc < 8; kc++){
          const int ko = (kc-4)*32 + kg*8;
          const s16x8 af = *(const s16x8*)&U1[15][l15][ko];
          const s16x8 w0 = *(const s16x8*)&r1Wb[(size_t)u0*256 + 128 + ko];
          const s16x8 w1 = *(const s16x8*)&r1Wb[(size_t)u1*256 + 128 + ko];
          c0 = mfma16(af, w0, c0);
          c1 = mfma16(af, w1, c1);
        }
        #pragma unroll
        for (int r = 0; r < 4; r++){
          const int m = kg*4 + r;
          out[(size_t)(f0+m)*256 + 128 + u0] = f2bf(fast_tanh(c0[r]));
          out[(size_t)(f0+m)*256 + 128 + u1] = f2bf(fast_tanh(c1[r]));
        }
      }
      lds_barrier();
      cur ^= 1;
    }
  }
}

// ---------------------------------------------------------------------------
// xw GEMM, operand-swapped, writing the gru v3 layout with 16B stores
// (unchanged from round 12).
// ---------------------------------------------------------------------------
__global__ __launch_bounds__(256) void gemm_xw(
    const u16* __restrict__ A,       // (16384,256) bf16 activations
    const u16* __restrict__ Wb,      // (768,256) bf16 weights
    const float* __restrict__ bih,   // (768)
    const float* __restrict__ bhhp,  // (768)
    float* __restrict__ xwT)         // (2,512,2,6144) f32, gru-native v3
{
  const int t = threadIdx.x;
  const int lane = t & 63, wv = t >> 6;
  const int l15 = lane & 15, kg = lane >> 4;
  const int ublk = blockIdx.x * 32;              // unit-block (24 blocks)
  const int f0 = blockIdx.y * 64 + wv*16;        // frame-block, 16/wave
  const u16* Ap = A  + (size_t)(f0 + l15)*256 + kg*8;
  const u16* W0 = Wb + (size_t)(ublk + l15)*256 + kg*8;
  const u16* W1 = Wb + (size_t)(ublk + 16 + l15)*256 + kg*8;
  const int c0 = ublk + kg*4, c1 = c0 + 16;
  f32x4 acc0 = *(const f32x4*)&bih[c0];
  f32x4 acc1 = *(const f32x4*)&bih[c1];
  const int cc0 = c0 >= 384 ? c0 - 384 : c0;
  const int cc1 = c1 >= 384 ? c1 - 384 : c1;
  if ((cc0 >> 7) < 2) acc0 += *(const f32x4*)&bhhp[c0];
  if ((cc1 >> 7) < 2) acc1 += *(const f32x4*)&bhhp[c1];
  #pragma unroll
  for (int kc = 0; kc < 8; kc++){
    const s16x8 a  = *(const s16x8*)(Ap + kc*32);
    const s16x8 w0 = *(const s16x8*)(W0 + kc*32);
    const s16x8 w1 = *(const s16x8*)(W1 + kc*32);
    acc0 = mfma16(w0, a, acc0);   // D rows = units, cols = frames
    acc1 = mfma16(w1, a, acc1);
  }
  const int f = f0 + l15, b = f >> 9, tt = f & 511;
  const int half = b >> 4, bl = b & 15;
  {
    const int d = c0 >= 384 ? 1 : 0;
    const int g = cc0 >> 7, u = cc0 & 127;
    const size_t idx = (((size_t)d*512 + tt)*2 + half)*6144
        + (size_t)(((u>>4)*4 + ((u>>2)&3))*16 + bl)*12 + g*4;
    *(f32x4*)&xwT[idx] = acc0;
  }
  {
    const int d = c1 >= 384 ? 1 : 0;
    const int g = cc1 >> 7, u = cc1 & 127;
    const size_t idx = (((size_t)d*512 + tt)*2 + half)*6144
        + (size_t)(((u>>4)*4 + ((u>>2)&3))*16 + bl)*12 + g*4;
    *(f32x4*)&xwT[idx] = acc1;
  }
}

// ---------------------------------------------------------------------------
// Weight prep (unchanged).
// ---------------------------------------------------------------------------
__global__ __launch_bounds__(256) void prep_kernel(
    const float* __restrict__ g0W, const float* __restrict__ g1W,
    const float* __restrict__ r1Wih,
    const float* __restrict__ r1bih, const float* __restrict__ r1bhh,
    u16* __restrict__ g0o, u16* __restrict__ g1o, u16* __restrict__ r1o,
    float* __restrict__ bo)
{
  const int i = blockIdx.x*256 + threadIdx.x;
  if (i < 196608){ g0o[i] = f2bf(g0W[i]); g1o[i] = f2bf(g1W[i]); }
  if (i < 32768)   r1o[i] = f2bf(r1Wih[32768 + i]);
  if (i < 128)     bo[i]  = r1bih[128+i] + r1bhh[128+i];
}

// ---------------------------------------------------------------------------
// GRU scan: EXACT round-8/12 structure (measured 305us).
// ---------------------------------------------------------------------------
__global__ __launch_bounds__(512, 1) void gru_mfma(
    const float* __restrict__ xwT,  // (2,512,2,6144) gru-native v3
    const float* __restrict__ Whh,  // (2,384,128) f32
    const float* __restrict__ bhh,  // (2,384)
    u16* __restrict__ hout)         // (16384,256) bf16
{
  __shared__ __align__(16) u16 h_lds[2][16][136];
  const int t = threadIdx.x;
  const int lane = t & 63, wv = t >> 6;
  const int l15 = lane & 15, kg = lane >> 4;
  const int dir = blockIdx.x & 1, half = blockIdx.x >> 1;
  s16x8 wa[3][4];
  {
    const float* Wd = Whh + (size_t)dir*49152;
    #pragma unroll
    for (int g = 0; g < 3; g++)
      #pragma unroll
      for (int kc = 0; kc < 4; kc++)
        wa[g][kc] = packfrag(&Wd[(size_t)(g*128 + wv*16 + l15)*128
                                 + kc*32 + kg*8]);
  }
  const f32x4 bhn = *(const f32x4*)&bhh[dir*384 + 256 + wv*16 + kg*4];
  if (t < 272) ((uint4*)h_lds)[t] = make_uint4(0,0,0,0);
  f32x4 hreg = {0.f,0.f,0.f,0.f};
  const long tstep = dir ? -49152L : 49152L;     // bytes per tt step
  const char* xb = (const char*)xwT
      + (((size_t)dir*512 + (dir ? 511 : 0))*2 + half)*24576
      + (size_t)(((wv*4 + kg)*16 + l15)*12)*4;
  f32x4 pa[3], pb[3];
  pa[0] = *(const f32x4*)(xb); pa[1] = *(const f32x4*)(xb+16); pa[2] = *(const f32x4*)(xb+32);
  xb += tstep;
  pb[0] = *(const f32x4*)(xb); pb[1] = *(const f32x4*)(xb+16); pb[2] = *(const f32x4*)(xb+32);
  xb += tstep;
  const int hstep = dir ? -256 : 256;            // u16 units per tt step
  int hoff = ((half*16 + l15)*512 + (dir ? 511 : 0))*256 + dir*128 + wv*16 + kg*4;
  lds_barrier();
  int cur = 0;

#define GSTEP(PX, DOLOAD)                                                   \
  {                                                                         \
    f32x4 a0 = PX[0], a1 = PX[1], a2 = bhn;                                 \
    const f32x4 cxn = PX[2];                                                \
    if (DOLOAD){                                                            \
      PX[0] = *(const f32x4*)(xb);                                          \
      PX[1] = *(const f32x4*)(xb+16);                                       \
      PX[2] = *(const f32x4*)(xb+32);                                       \
      xb += tstep;                                                          \
    }                                                                       \
    __builtin_amdgcn_s_setprio(1);                                          \
    _Pragma("unroll")                                                       \
    for (int kc = 0; kc < 4; kc++){                                         \
      const s16x8 hf = *(const s16x8*)&h_lds[cur][l15][kc*32 + kg*8];       \
      a0 = mfma16(wa[0][kc], hf, a0);                                       \
      a1 = mfma16(wa[1][kc], hf, a1);                                       \
      a2 = mfma16(wa[2][kc], hf, a2);                                       \
    }                                                                       \
    __builtin_amdgcn_s_setprio(0);                                          \
    float hn[4];                                                            \
    _Pragma("unroll")                                                       \
    for (int r = 0; r < 4; r++){                                            \
      const float rr = fast_sigmoid(a0[r]);                                 \
      const float zz = fast_sigmoid(a1[r]);                                 \
      const float nn = fast_tanh(fmaf(rr, a2[r], cxn[r]));                  \
      hn[r] = fmaf(zz, hreg[r] - nn, nn);                                   \
      hreg[r] = hn[r];                                                      \
    }                                                                       \
    const uint2 hp = make_uint2(cvt_pk_bf16(hn[0],hn[1]),                   \
                                cvt_pk_bf16(hn[2],hn[3]));                  \
    *(uint2*)&h_lds[cur^1][l15][wv*16 + kg*4] = hp;                         \
    *(uint2*)&hout[hoff] = hp;                                              \
    hoff += hstep;                                                          \
    lds_barrier();                                                          \
    cur ^= 1;                                                               \
  }

  for (int ti = 0; ti < 510; ti += 2){
    GSTEP(pa, 1);
    GSTEP(pb, 1);
  }
  GSTEP(pa, 0);   // step 510
  GSTEP(pb, 0);   // step 511
#undef GSTEP
}

__global__ void prefix_kernel(const int* __restrict__ lengths, int* __restrict__ pre){
  if (threadIdx.x == 0 && blockIdx.x == 0){
    int run = 0;
    for (int b = 0; b < 32; b++){ pre[b] = run; run += lengths[b]; }
  }
}

// ---------------------------------------------------------------------------
// Final FC (61 x 256) + ragged masked scatter into d_out (unchanged).
// ---------------------------------------------------------------------------
__global__ __launch_bounds__(256) void fc_kernel(
    const u16* __restrict__ A,      // (16384,256) bf16
    const float* __restrict__ W,    // (61,256)
    const float* __restrict__ bias, // (61)
    const int* __restrict__ lengths,
    const int* __restrict__ pre,
    float* __restrict__ out)
{
  __shared__ __align__(16) float4 Wl[64][61];
  __shared__ __align__(16) float  Al[64][256];
  const int t = threadIdx.x;
  const int row0 = blockIdx.x * 64;
  for (int idx = t; idx < 61*64; idx += 256){
    int c = idx >> 6, k4 = idx & 63;
    Wl[k4][c] = *(const float4*)&W[(size_t)c*256 + k4*4];
  }
  {
    const u32* A32 = (const u32*)(A + (size_t)row0*256);
    for (int idx = t; idx < 8192; idx += 256){
      u32 v = A32[idx];
      int r = idx >> 7, kp = idx & 127;
      Al[r][2*kp]   = bflo(v);
      Al[r][2*kp+1] = bfhi(v);
    }
  }
  __syncthreads();
  const int c = t & 63;
  const int rbase = t >> 6;
  if (c < 61){
    const float bv = bias[c];
    for (int rr = rbase; rr < 64; rr += 4){
      float s0=0,s1=0,s2=0,s3=0;
      const float4* Ap = (const float4*)&Al[rr][0];
      #pragma unroll
      for (int k4 = 0; k4 < 64; k4++){
        const float4 w = Wl[k4][c];
        const float4 a = Ap[k4];
        s0 = fmaf(w.x, a.x, s0);
        s1 = fmaf(w.y, a.y, s1);
        s2 = fmaf(w.z, a.z, s2);
        s3 = fmaf(w.w, a.w, s3);
      }
      const int n = row0 + rr;
      const int b = n >> 9, tt = n & 511;
      if (tt < lengths[b])
        out[(size_t)(pre[b] + tt)*61 + c] = bv + s0+s1+s2+s3;
    }
  }
}

extern "C" void kernel_launch(void* const* d_in, const int* in_sizes, int n_in,
                              void* d_out, int out_size, void* d_ws, size_t ws_size,
                              hipStream_t stream)
{
  const float* x     = (const float*)d_in[0];
  const int*   lens  = (const int*)d_in[1];
  const float* r0Wih = (const float*)d_in[2];
  const float* r0Whh = (const float*)d_in[3];
  const float* r0bih = (const float*)d_in[4];
  const float* r0bhh = (const float*)d_in[5];
  const float* r1Wih = (const float*)d_in[6];
  const float* r1Whh = (const float*)d_in[7];
  const float* r1bih = (const float*)d_in[8];
  const float* r1bhh = (const float*)d_in[9];
  const float* g0Wih = (const float*)d_in[10];
  const float* g0Whh = (const float*)d_in[11];
  const float* g0bih = (const float*)d_in[12];
  const float* g0bhh = (const float*)d_in[13];
  const float* g1Wih = (const float*)d_in[14];
  const float* g1Whh = (const float*)d_in[15];
  const float* g1bih = (const float*)d_in[16];
  const float* g1bhh = (const float*)d_in[17];
  const float* fcW   = (const float*)d_in[18];
  const float* fcb   = (const float*)d_in[19];
  float* out = (float*)d_out;

  char* ws = (char*)d_ws;
  float* xwbuf = (float*)(ws);                      // xwT (2,512,2,6144) f32
  u16*   g0out = (u16*)(ws + 50331648);
  u16*   g0Wb  = (u16*)(ws + 58720256);             // 393216 B
  u16*   g1Wb  = (u16*)(ws + 58720256 + 393216);    // 393216 B
  u16*   r1Wb  = (u16*)(ws + 58720256 + 786432);    // 65536 B
  float* biasb = (float*)(ws + 58720256 + 851968);  // 512 B
  u16*   g1out = (u16*)(ws + 58720256);             // overwrites prep late
  u16*   rnn1  = (u16*)(ws + 67108864);
  int*   pre   = (int*)(ws + 75497472);

  prep_kernel<<<768, 256, 0, stream>>>(g0Wih, g1Wih, r1Wih, r1bih, r1bhh,
                                       g0Wb, g1Wb, r1Wb, biasb);
  // fused rnn1 (both layers), no intermediate HBM buffer, no chunk loop
  rnn1_fused<<<NF_/16, 256, 0, stream>>>(
      x, r0Wih, r0Whh, r0bih, r0bhh,
      r1Wih, r1Whh, r1bih, r1bhh, r1Wb, biasb, rnn1);
  // GRU layer 0
  gemm_xw<<<dim3(24, NF_/64), 256, 0, stream>>>(
      rnn1, g0Wb, g0bih, g0bhh, xwbuf);
  gru_mfma<<<4, 512, 0, stream>>>(xwbuf, g0Whh, g0bhh, g0out);
  // GRU layer 1
  gemm_xw<<<dim3(24, NF_/64), 256, 0, stream>>>(
      g0out, g1Wb, g1bih, g1bhh, xwbuf);
  gru_mfma<<<4, 512, 0, stream>>>(xwbuf, g1Whh, g1bhh, g1out);
  // FC + ragged scatter
  prefix_kernel<<<1, 64, 0, stream>>>(lens, pre);
  fc_kernel<<<NF_/64, 256, 0, stream>>>(g1out, fcW, fcb, lens, pre, out);
}